// Round 1
// baseline (844.201 us; speedup 1.0000x reference)
//
#include <hip/hip_runtime.h>
#include <math.h>

// NaryTreeLSTM on MI355X — round 11: fat-A gate GEMM.
// R10 diagnosis: gate_gemm was staging-BW bound — A panel re-staged by all
// N/BN=10 column blocks (670 MB moved per d=15 dispatch vs 35 MB useful),
// MfmaUtil 14% with a 21 µs MFMA floor inside a 119 µs dispatch.
// Fix: one block per 128 rows keeps the FULL K=512 A panel resident in
// 128 KB LDS (staged once via global_load_lds with counted-vmcnt per-slice
// gating), loops over 256-col output chunks; B fragments are read directly
// from the frag-major Wfrag (L2-hot) — no B staging, no barriers after the
// first chunk. 8 waves (2 row x 4 col), __launch_bounds__(512,2).
// Small levels split col chunks across blockIdx.y to keep latency low.

#define LEAF_N 65536

typedef __attribute__((ext_vector_type(8))) short bf16x8;
typedef __attribute__((ext_vector_type(4))) float f32x4;
typedef unsigned short u16;

__device__ __forceinline__ float fast_sig(float x) {
    return __builtin_amdgcn_rcpf(1.0f + __expf(-x));
}
__device__ __forceinline__ float fast_tanh(float x) {
    return 2.0f * __builtin_amdgcn_rcpf(1.0f + __expf(-2.0f * x)) - 1.0f;
}

__device__ __forceinline__ u16 f2bf(float f) {
    union { float f; unsigned u; } v; v.f = f;
    unsigned r = v.u + 0x7fffu + ((v.u >> 16) & 1u);   // RNE
    return (u16)(r >> 16);
}

// row-major Z offset (elems) for levels d in [5,15]
__host__ __device__ __forceinline__ size_t zrowOff(int d) {
    return (size_t)(65536 - (2 << d)) * 512;
}

__device__ __forceinline__ void gld_lds16(const u16* g, u16* s) {
    __builtin_amdgcn_global_load_lds(
        (const __attribute__((address_space(1))) void*)g,
        (__attribute__((address_space(3))) void*)s, 16, 0, 0);
}

template<int N> __device__ __forceinline__ void wait_vm() {
    asm volatile("s_waitcnt vmcnt(%0)" :: "n"(N) : "memory");
}

// ---------------- weight packing ----------------
// Wfrag: frag-major 1280x512 big matrix ([i|Ui],[o|Uo],[u|Uu],[f|Wfk0],[f|Wfk1]):
//   addr = ((nt*16+kc)*64 + l)*8 + j ; row=nt*16+(l&15), k=kc*32+(l>>4)*8+j
// WleafFrag: frag-major 768x256 ([i;o;u]):
//   addr = ((nt*8+kc)*64 + l)*8 + j  (kc in [0,8))
__global__ __launch_bounds__(256) void pack_weights(
    const float* __restrict__ Wi, const float* __restrict__ bi,
    const float* __restrict__ Wf, const float* __restrict__ bf,
    const float* __restrict__ Wo, const float* __restrict__ bo,
    const float* __restrict__ Wu, const float* __restrict__ bu,
    const float* __restrict__ Ui, const float* __restrict__ Uo,
    const float* __restrict__ Uu, const float* __restrict__ Wfk,
    u16* __restrict__ Wfrag, u16* __restrict__ WleafFrag,
    float* __restrict__ bbig, float* __restrict__ bleaf)
{
    int idx = blockIdx.x * 256 + threadIdx.x;
    const int NWB = 1280 * 512;
    const int NWL = 768 * 256;

    auto bigval = [&](int row, int k) -> float {
        int g = row >> 8, rr = row & 255;
        if (k < 256) {
            const float* W = (g == 0) ? Wi : (g == 1) ? Wo : (g == 2) ? Wu : Wf;
            return W[rr * 256 + k];
        }
        int kk = k - 256;
        return (g == 0) ? Ui[rr * 256 + kk]
             : (g == 1) ? Uo[rr * 256 + kk]
             : (g == 2) ? Uu[rr * 256 + kk]
             : (g == 3) ? Wfk[rr * 256 + kk]
                        : Wfk[65536 + rr * 256 + kk];
    };

    if (idx < NWB) {
        int q = idx;
        int j = q & 7, l = (q >> 3) & 63, kc = (q >> 9) & 15, nt = q >> 13;
        int row = nt * 16 + (l & 15);
        int k = kc * 32 + ((l >> 4) << 3) + j;
        Wfrag[q] = f2bf(bigval(row, k));
    } else if (idx < NWB + NWL) {
        int q = idx - NWB;
        int j = q & 7, l = (q >> 3) & 63, kc = (q >> 9) & 7, nt = q >> 12;
        int row = nt * 16 + (l & 15);
        int k = kc * 32 + ((l >> 4) << 3) + j;
        int g = row >> 8, rr = row & 255;
        const float* W = (g == 0) ? Wi : (g == 1) ? Wo : Wu;
        WleafFrag[q] = f2bf(W[rr * 256 + k]);
    } else if (idx < NWB + NWL + 1280) {
        int r = idx - NWB - NWL;
        int g = r >> 8, rr = r & 255;
        bbig[r] = (g == 0) ? bi[rr] : (g == 1) ? bo[rr] : (g == 2) ? bu[rr] : bf[rr];
    } else if (idx < NWB + NWL + 1280 + 768) {
        int r = idx - NWB - NWL - 1280;
        int g = r >> 8, rr = r & 255;
        bleaf[r] = (g == 0) ? bi[rr] : (g == 1) ? bo[rr] : bu[rr];
    }
}

// ---------------- x -> bf16 conversion ----------------
// d>=5: row-major Zrow; d<=4: frag-major tile at Ztiles+(4-d)*8192; leaf: Xbf.
__global__ __launch_bounds__(256) void cvt_all(
    const float* __restrict__ x, u16* __restrict__ Zrow,
    u16* __restrict__ Ztiles, u16* __restrict__ Xbf)
{
    int idx = blockIdx.x * 256 + threadIdx.x;
    if (idx >= 131071 * 32) return;
    int row = idx >> 5, k8 = idx & 31;
    const float* s = x + (size_t)row * 256 + k8 * 8;
    u16 r[8];
#pragma unroll
    for (int i = 0; i < 8; i++) r[i] = f2bf(s[i]);
    if (row < 65535) {
        int d = 31 - __clz(row + 1);
        int jn = row - ((1 << d) - 1);
        if (d >= 5) {
            *(uint4*)(Zrow + zrowOff(d) + (size_t)jn * 512 + k8 * 8) = *(uint4*)r;
        } else {
            int kc = k8 >> 2;
            int l = (jn & 15) + ((k8 & 3) << 4);
            size_t dst = (size_t)(4 - d) * 8192 + ((size_t)kc * 64 + l) * 8;
            *(uint4*)(Ztiles + dst) = *(uint4*)r;
        }
    } else {
        int jn = row - 65535;
        *(uint4*)(Xbf + (size_t)jn * 256 + k8 * 8) = *(uint4*)r;
    }
}

// ---------------- stage 1: fat-A gate GEMM ----------------
// C = act(A @ B^T + bias) -> fp16.  act: tanh for cols [512,768), sigmoid else.
// Block: 128 rows, full K resident in LDS (XOR-swizzled slices of 128x64),
// loops over 256-col chunks [nc0, ncEnd). B frags from frag-major Wf (L2).
// 8 waves: wr = wave>>2 (row half), wc = wave&3 (64-col quarter of chunk).
template<int KD, int NCH>
__global__ __launch_bounds__(512, 2) void gate_gemm(
    const u16* __restrict__ A, int M,
    const u16* __restrict__ Wf, const float* __restrict__ bias,
    _Float16* __restrict__ G, int chunks_per)
{
    constexpr int NSL = KD / 64;     // k-slices of 64
    constexpr int KC  = KD / 32;     // frag k-chunks of 32
    constexpr int NC  = NCH * 256;
    extern __shared__ u16 As[];      // [NSL][128][64] swizzled, NSL*16 KB

    const int tid  = threadIdx.x;
    const int wave = tid >> 6;
    const int lane = tid & 63;
    const int bm = blockIdx.x * 128;
    const int nc0 = blockIdx.y * chunks_per;
    if (nc0 >= NCH) return;
    int ncEnd = nc0 + chunks_per; if (ncEnd > NCH) ncEnd = NCH;

    // ---- issue ALL A staging up front (slice-major => oldest = slice 0) ----
    // group g = wave*2+q covers rows g*8 + (lane>>3); lane fetches swizzled
    // col ((lane&7)^(lane>>3))*8 of its row (same 128B segment).
    {
        const int srow = lane >> 3;
        const int scol = ((lane & 7) ^ srow) * 8;
#pragma unroll
        for (int kc = 0; kc < NSL; ++kc) {
#pragma unroll
            for (int q = 0; q < 2; ++q) {
                const int g = wave * 2 + q;
                gld_lds16(A + (size_t)(bm + g * 8 + srow) * KD + kc * 64 + scol,
                          As + kc * 8192 + g * 512 + lane * 8);
            }
        }
    }

    const int wr = wave >> 2;
    const int wc = wave & 3;
    const int wm = wr * 64;
    const int lm = lane & 15, q4 = lane >> 4;

    const u16* sa = As + (wm + lm) * 64;           // A frag base (per thread)

    for (int nc = nc0; nc < ncEnd; ++nc) {
        f32x4 acc[4][4] = {};
        // B frag base for this chunk: col-tile nt = nc*16 + wc*4 + j
        const u16* wfb = Wf + ((size_t)(nc * 16 + wc * 4) * KC) * 512 + lane * 8;

#pragma unroll
        for (int kc8 = 0; kc8 < NSL; ++kc8) {
            if (nc == nc0) {
                // counted-vmcnt gate: wave's first 2*(kc8+1) A-loads done.
                // (B loads issued later are younger -> A gating still holds.)
#define WVM(k) case k: wait_vm<(2*(NSL-1-(k)) > 0 ? 2*(NSL-1-(k)) : 0)>(); break;
                switch (kc8) { WVM(0) WVM(1) WVM(2) WVM(3) WVM(4) WVM(5) WVM(6) WVM(7) }
#undef WVM
                __builtin_amdgcn_s_barrier();
                __builtin_amdgcn_sched_barrier(0);
            }
#pragma unroll
            for (int kk = 0; kk < 64; kk += 32) {
                const int sw = ((((kk >> 3) + q4) ^ (lm & 7)) << 3);
                const int kc = kc8 * 2 + (kk >> 5);
                bf16x8 af[4], bfr[4];
#pragma unroll
                for (int i = 0; i < 4; i++)
                    af[i] = *(const bf16x8*)(sa + kc8 * 8192 + i * 1024 + sw);
#pragma unroll
                for (int j = 0; j < 4; j++)
                    bfr[j] = *(const bf16x8*)(wfb + (size_t)(j * KC + kc) * 512);
#pragma unroll
                for (int i = 0; i < 4; i++)
#pragma unroll
                    for (int j = 0; j < 4; j++)
                        acc[i][j] = __builtin_amdgcn_mfma_f32_16x16x32_bf16(
                            af[i], bfr[j], acc[i][j], 0, 0, 0);
            }
        }

        // epilogue: activate + store fp16 chunk tile
        const int cr0 = q4 * 4;
#pragma unroll
        for (int i = 0; i < 4; i++) {
#pragma unroll
            for (int j = 0; j < 4; j++) {
                const int cg = nc * 256 + wc * 64 + j * 16 + lm;
                const float bb = bias[cg];
                const bool istan = ((cg >> 8) == 2);
#pragma unroll
                for (int reg = 0; reg < 4; reg++) {
                    const int rr = bm + wm + i * 16 + cr0 + reg;
                    if (rr >= M) continue;
                    float v = acc[i][j][reg] + bb;
                    G[(size_t)rr * NC + cg] =
                        (_Float16)(istan ? fast_tanh(v) : fast_sig(v));
                }
            }
        }
    }
}

// ---------------- stage 2: combine ----------------
template<bool LEAF>
__global__ __launch_bounds__(256) void combine(
    const _Float16* __restrict__ G, const float* __restrict__ csrc,
    float* __restrict__ cdst, u16* __restrict__ zrow_parent,
    u16* __restrict__ zfrag_parent)
{
    constexpr int NC = LEAF ? 768 : 1280;
    const int p = blockIdx.x, h = threadIdx.x;
    const _Float16* G0 = G + (size_t)(2 * p) * NC;
    const _Float16* G1 = G0 + NC;
    float i0 = (float)G0[h], o0 = (float)G0[256 + h], u0 = (float)G0[512 + h];
    float i1 = (float)G1[h], o1 = (float)G1[256 + h], u1 = (float)G1[512 + h];
    float c0 = i0 * u0, c1 = i1 * u1;
    if (!LEAF) {
        float f00 = (float)G0[768 + h], f10 = (float)G0[1024 + h];
        float f01 = (float)G1[768 + h], f11 = (float)G1[1024 + h];
        c0 += f00 * csrc[(size_t)(4 * p) * 256 + h]
            + f10 * csrc[(size_t)(4 * p + 1) * 256 + h];
        c1 += f01 * csrc[(size_t)(4 * p + 2) * 256 + h]
            + f11 * csrc[(size_t)(4 * p + 3) * 256 + h];
    }
    float h0 = o0 * fast_tanh(c0), h1 = o1 * fast_tanh(c1);
    cdst[(size_t)(2 * p) * 256 + h] = c0;
    cdst[(size_t)(2 * p) * 256 + 256 + h] = c1;
    u16 hs = f2bf(h0 + h1);
    if (zrow_parent) {
        zrow_parent[(size_t)p * 512 + 256 + h] = hs;
    } else {
        size_t a = (((size_t)8 + (h >> 5)) * 64
                    + (p & 15) + (((h >> 3) & 3) << 4)) * 8 + (h & 7);
        zfrag_parent[a] = hs;
    }
}

// ---------------- small levels (n<=16): gate-parallel GEMM -> pre ----------
__global__ __launch_bounds__(64) void small_gemm(
    const u16* __restrict__ Zpk, const u16* __restrict__ Wfrag,
    const float* __restrict__ bias, float* __restrict__ pre, int n)
{
    const int lane = threadIdx.x;
    const int q = blockIdx.x;
    const int nt0 = (q >> 2) * 16 + (q & 3) * 4;
    const int cc = lane & 15, rq = (lane >> 4) * 4;

    f32x4 acc[4] = {};
    const u16* aB = Zpk + (size_t)lane * 8;
    const u16* bB = Wfrag + ((size_t)nt0 * 16 * 64 + lane) * 8;

    bf16x8 aX, bX[4], aY, bY[4];
    aX = *(const bf16x8*)(aB);
#pragma unroll
    for (int j = 0; j < 4; ++j)
        bX[j] = *(const bf16x8*)(bB + (size_t)(j * 16) * 512);

#pragma unroll
    for (int kc = 0; kc < 16; kc += 2) {
        aY = *(const bf16x8*)(aB + (size_t)(kc + 1) * 512);
#pragma unroll
        for (int j = 0; j < 4; ++j)
            bY[j] = *(const bf16x8*)(bB + (size_t)(j * 16 + kc + 1) * 512);
#pragma unroll
        for (int j = 0; j < 4; ++j)
            acc[j] = __builtin_amdgcn_mfma_f32_16x16x32_bf16(aX, bX[j], acc[j], 0, 0, 0);
        if (kc + 2 < 16) {
            aX = *(const bf16x8*)(aB + (size_t)(kc + 2) * 512);
#pragma unroll
            for (int j = 0; j < 4; ++j)
                bX[j] = *(const bf16x8*)(bB + (size_t)(j * 16 + kc + 2) * 512);
        }
#pragma unroll
        for (int j = 0; j < 4; ++j)
            acc[j] = __builtin_amdgcn_mfma_f32_16x16x32_bf16(aY, bY[j], acc[j], 0, 0, 0);
    }

#pragma unroll
    for (int j = 0; j < 4; ++j) {
        int coln = (nt0 + j) * 16 + cc;
        float bb = bias[coln];
#pragma unroll
        for (int r = 0; r < 4; ++r) {
            int row = rq + r;
            if (row < n) pre[(size_t)row * 1280 + coln] = acc[j][r] + bb;
        }
    }
}

// ---------------- small-level epilogue (pre -> c, Hs; root -> out) ----------
__global__ __launch_bounds__(256) void epi_small(
    const float* __restrict__ pre, const float* __restrict__ csrc,
    float* __restrict__ c_out, u16* __restrict__ zfrag_parent,
    float* __restrict__ root_out, int npairs)
{
    int idx = blockIdx.x * 256 + threadIdx.x;
    if (root_out) {
        int h = idx;  // 256 threads
        const float* p = pre;
        float c = fast_sig(p[h]) * fast_tanh(p[512 + h])
                + fast_sig(p[768 + h]) * csrc[h]
                + fast_sig(p[1024 + h]) * csrc[256 + h];
        root_out[h] = fast_sig(p[256 + h]) * fast_tanh(c);
        root_out[256 + h] = c;
        return;
    }
    if (idx >= npairs * 256) return;
    int pI = idx >> 8, h = idx & 255;
    int n0 = 2 * pI;
    const float* p0 = pre + (size_t)n0 * 1280;
    const float* p1 = p0 + 1280;
    float c0 = fast_sig(p0[h]) * fast_tanh(p0[512 + h])
             + fast_sig(p0[768 + h]) * csrc[(size_t)(2 * n0) * 256 + h]
             + fast_sig(p0[1024 + h]) * csrc[(size_t)(2 * n0 + 1) * 256 + h];
    float c1 = fast_sig(p1[h]) * fast_tanh(p1[512 + h])
             + fast_sig(p1[768 + h]) * csrc[(size_t)(2 * n0 + 2) * 256 + h]
             + fast_sig(p1[1024 + h]) * csrc[(size_t)(2 * n0 + 3) * 256 + h];
    float h0 = fast_sig(p0[256 + h]) * fast_tanh(c0);
    float h1 = fast_sig(p1[256 + h]) * fast_tanh(c1);
    c_out[(size_t)n0 * 256 + h] = c0;
    c_out[(size_t)(n0 + 1) * 256 + h] = c1;
    size_t a = (((size_t)8 + (h >> 5)) * 64
                + (pI & 15) + (((h >> 3) & 3) << 4)) * 8 + (h & 7);
    zfrag_parent[a] = f2bf(h0 + h1);
}

// ---------------- launch ----------------
extern "C" void kernel_launch(void* const* d_in, const int* in_sizes, int n_in,
                              void* d_out, int out_size, void* d_ws, size_t ws_size,
                              hipStream_t stream)
{
    const float* x   = (const float*)d_in[0];
    const float* Wi  = (const float*)d_in[1];
    const float* bi  = (const float*)d_in[2];
    const float* Wf  = (const float*)d_in[3];
    const float* bf  = (const float*)d_in[4];
    const float* Wo  = (const float*)d_in[5];
    const float* bo  = (const float*)d_in[6];
    const float* Wu  = (const float*)d_in[7];
    const float* bu  = (const float*)d_in[8];
    const float* Ui  = (const float*)d_in[9];
    const float* Uo  = (const float*)d_in[10];
    const float* Uu  = (const float*)d_in[11];
    const float* Wfk = (const float*)d_in[12];
    float* out = (float*)d_out;
    char* ws   = (char*)d_ws;
    (void)ws_size; (void)in_sizes; (void)n_in; (void)out_size;

    size_t off = 0;
    u16* Wfrag     = (u16*)(ws + off); off += (size_t)1280 * 512 * 2;
    u16* WleafFrag = (u16*)(ws + off); off += (size_t)768 * 256 * 2;
    float* bbig   = (float*)(ws + off); off += 1280 * 4;
    float* bleaf  = (float*)(ws + off); off += 768 * 4 + 192;                // 256B align
    u16* Xbf    = (u16*)(ws + off); off += (size_t)65536 * 256 * 2;          // 32 MB
    u16* Zrow   = (u16*)(ws + off); off += (size_t)65536 * 512 * 2;          // 64 MB
    u16* Ztiles = (u16*)(ws + off); off += (size_t)5 * 8192 * 2;             // 80 KB
    float* cA = (float*)(ws + off); off += (size_t)65536 * 256 * 4;          // 64 MB
    float* cB = (float*)(ws + off); off += (size_t)32768 * 256 * 4;          // 32 MB
    float* pre_small = (float*)(ws + off); off += (size_t)16 * 1280 * 4;
    _Float16* Ghalf = (_Float16*)(ws + off); off += (size_t)65536 * 768 * 2; // 96 MB

    auto ztile = [&](int d) -> u16* { return Ztiles + (size_t)(4 - d) * 8192; };

    // allow >64KB dynamic LDS for the big-K gemm (idempotent, host-side only)
    static bool attr_set = false;
    if (!attr_set) {
        hipFuncSetAttribute((const void*)gate_gemm<512, 5>,
                            hipFuncAttributeMaxDynamicSharedMemorySize, 131072);
        hipFuncSetAttribute((const void*)gate_gemm<256, 3>,
                            hipFuncAttributeMaxDynamicSharedMemorySize, 65536);
        attr_set = true;
    }

    // 1) pack weights + convert x
    pack_weights<<<3336, 256, 0, stream>>>(Wi, bi, Wf, bf, Wo, bo, Wu, bu,
                                           Ui, Uo, Uu, Wfk, Wfrag, WleafFrag,
                                           bbig, bleaf);
    cvt_all<<<16385, 256, 0, stream>>>(x, Zrow, Ztiles, Xbf);

    // 2) leaf: gemm (i,o,u fp16) + combine -> cA, Hs into Zrow level 15
    gate_gemm<256, 3><<<dim3(LEAF_N / 128, 1), 512, 65536, stream>>>(
        Xbf, LEAF_N, WleafFrag, bleaf, Ghalf, 3);
    combine<true><<<LEAF_N / 2, 256, 0, stream>>>(
        Ghalf, nullptr, cA, Zrow + zrowOff(15), nullptr);

    // 3) internal levels d=15..5
    for (int d = 15; d >= 5; d--) {
        int n = 1 << d;
        float* csrc = (d & 1) ? cA : cB;
        float* cdst = (d & 1) ? cB : cA;
        int bx = (n + 127) / 128;
        int cs = 256 / bx; if (cs < 1) cs = 1; if (cs > 5) cs = 5;
        int cp = (5 + cs - 1) / cs;
        gate_gemm<512, 5><<<dim3(bx, cs), 512, 131072, stream>>>(
            Zrow + zrowOff(d), n, Wfrag, bbig, Ghalf, cp);
        if (d >= 6)
            combine<false><<<n / 2, 256, 0, stream>>>(
                Ghalf, csrc, cdst, Zrow + zrowOff(d - 1), nullptr);
        else
            combine<false><<<n / 2, 256, 0, stream>>>(
                Ghalf, csrc, cdst, nullptr, ztile(4));
    }

    // 4) small levels d=4..1: frag-major gate-parallel gemm + epilogue
    for (int d = 4; d >= 1; d--) {
        int n = 1 << d;
        float* csrc = (d & 1) ? cA : cB;
        float* cdst = (d & 1) ? cB : cA;
        small_gemm<<<20, 64, 0, stream>>>(ztile(d), Wfrag, bbig, pre_small, n);
        epi_small<<<n / 2, 256, 0, stream>>>(pre_small, csrc, cdst,
                                             ztile(d - 1), nullptr, n / 2);
    }

    // 5) root: gemm + epilogue straight to out = [h(256)|c(256)]
    small_gemm<<<20, 64, 0, stream>>>(ztile(0), Wfrag, bbig, pre_small, 1);
    epi_small<<<1, 256, 0, stream>>>(pre_small, cB, nullptr, nullptr, out, 0);
}

// Round 2
// 774.222 us; speedup vs baseline: 1.0904x; 1.0904x over previous
//
#include <hip/hip_runtime.h>
#include <math.h>

// NaryTreeLSTM on MI355X — round 12: 256x256 double-buffered 2-phase GEMM.
// R11 post-mortem: fat-A (B-from-L2) was latency-bound (2 waves/SIMD, no
// prefetch depth, 84 VGPR) — FETCH dropped 4x but time rose. Root cause of
// BOTH rounds: exposed stage drain (vmcnt(0)+barrier right after issuing the
// k-step's loads). Fix per guide T3-minimum: issue STAGE(t+1) BEFORE
// computing step t, single vmcnt(0)+barrier per step (double-buffered LDS),
// 256x256 tile / 8 waves (per-wave 128x64 out: 24 ds_read_b128 : 64 MFMA).
// Keeps R10's verified XOR-swizzle staging + fragment math. Big levels
// (leaf, d>=13) use the new kernel; d<=12 keeps the R10 128^2 kernel.

#define LEAF_N 65536

typedef __attribute__((ext_vector_type(8))) short bf16x8;
typedef __attribute__((ext_vector_type(4))) float f32x4;
typedef unsigned short u16;

__device__ __forceinline__ float fast_sig(float x) {
    return __builtin_amdgcn_rcpf(1.0f + __expf(-x));
}
__device__ __forceinline__ float fast_tanh(float x) {
    return 2.0f * __builtin_amdgcn_rcpf(1.0f + __expf(-2.0f * x)) - 1.0f;
}

__device__ __forceinline__ u16 f2bf(float f) {
    union { float f; unsigned u; } v; v.f = f;
    unsigned r = v.u + 0x7fffu + ((v.u >> 16) & 1u);   // RNE
    return (u16)(r >> 16);
}

// row-major Z offset (elems) for levels d in [5,15]
__host__ __device__ __forceinline__ size_t zrowOff(int d) {
    return (size_t)(65536 - (2 << d)) * 512;
}

__device__ __forceinline__ void gld_lds16(const u16* g, u16* s) {
    __builtin_amdgcn_global_load_lds(
        (const __attribute__((address_space(1))) void*)g,
        (__attribute__((address_space(3))) void*)s, 16, 0, 0);
}

// ---------------- weight packing ----------------
// Wrow: row-major 1280x512 ([i|Ui],[o|Uo],[u|Uu],[f|Wfk0],[f|Wfk1])
// Wfrag: frag-major same matrix (small_gemm):
//   addr = ((nt*16+kc)*64 + l)*8 + j ; row=nt*16+(l&15), k=kc*32+(l>>4)*8+j
// WleafRow: row-major 768x256 ([i;o;u])
__global__ __launch_bounds__(256) void pack_weights(
    const float* __restrict__ Wi, const float* __restrict__ bi,
    const float* __restrict__ Wf, const float* __restrict__ bf,
    const float* __restrict__ Wo, const float* __restrict__ bo,
    const float* __restrict__ Wu, const float* __restrict__ bu,
    const float* __restrict__ Ui, const float* __restrict__ Uo,
    const float* __restrict__ Uu, const float* __restrict__ Wfk,
    u16* __restrict__ Wrow, u16* __restrict__ Wfrag, u16* __restrict__ WleafRow,
    float* __restrict__ bbig, float* __restrict__ bleaf)
{
    int idx = blockIdx.x * 256 + threadIdx.x;
    const int NWB = 1280 * 512;
    const int NWL = 768 * 256;

    auto bigval = [&](int row, int k) -> float {
        int g = row >> 8, rr = row & 255;
        if (k < 256) {
            const float* W = (g == 0) ? Wi : (g == 1) ? Wo : (g == 2) ? Wu : Wf;
            return W[rr * 256 + k];
        }
        int kk = k - 256;
        return (g == 0) ? Ui[rr * 256 + kk]
             : (g == 1) ? Uo[rr * 256 + kk]
             : (g == 2) ? Uu[rr * 256 + kk]
             : (g == 3) ? Wfk[rr * 256 + kk]
                        : Wfk[65536 + rr * 256 + kk];
    };

    if (idx < NWB) {
        Wrow[idx] = f2bf(bigval(idx >> 9, idx & 511));
    } else if (idx < 2 * NWB) {
        int q = idx - NWB;
        int j = q & 7, l = (q >> 3) & 63, kc = (q >> 9) & 15, nt = q >> 13;
        int row = nt * 16 + (l & 15);
        int k = kc * 32 + ((l >> 4) << 3) + j;
        Wfrag[q] = f2bf(bigval(row, k));
    } else if (idx < 2 * NWB + NWL) {
        int q = idx - 2 * NWB;
        int r = q >> 8, k = q & 255;
        int g = r >> 8, rr = r & 255;
        const float* W = (g == 0) ? Wi : (g == 1) ? Wo : Wu;
        WleafRow[q] = f2bf(W[rr * 256 + k]);
    } else if (idx < 2 * NWB + NWL + 1280) {
        int r = idx - 2 * NWB - NWL;
        int g = r >> 8, rr = r & 255;
        bbig[r] = (g == 0) ? bi[rr] : (g == 1) ? bo[rr] : (g == 2) ? bu[rr] : bf[rr];
    } else if (idx < 2 * NWB + NWL + 1280 + 768) {
        int r = idx - 2 * NWB - NWL - 1280;
        int g = r >> 8, rr = r & 255;
        bleaf[r] = (g == 0) ? bi[rr] : (g == 1) ? bo[rr] : bu[rr];
    }
}

// ---------------- x -> bf16 conversion ----------------
// d>=5: row-major Zrow; d<=4: frag-major tile at Ztiles+(4-d)*8192; leaf: Xbf.
__global__ __launch_bounds__(256) void cvt_all(
    const float* __restrict__ x, u16* __restrict__ Zrow,
    u16* __restrict__ Ztiles, u16* __restrict__ Xbf)
{
    int idx = blockIdx.x * 256 + threadIdx.x;
    if (idx >= 131071 * 32) return;
    int row = idx >> 5, k8 = idx & 31;
    const float* s = x + (size_t)row * 256 + k8 * 8;
    u16 r[8];
#pragma unroll
    for (int i = 0; i < 8; i++) r[i] = f2bf(s[i]);
    if (row < 65535) {
        int d = 31 - __clz(row + 1);
        int jn = row - ((1 << d) - 1);
        if (d >= 5) {
            *(uint4*)(Zrow + zrowOff(d) + (size_t)jn * 512 + k8 * 8) = *(uint4*)r;
        } else {
            int kc = k8 >> 2;
            int l = (jn & 15) + ((k8 & 3) << 4);
            size_t dst = (size_t)(4 - d) * 8192 + ((size_t)kc * 64 + l) * 8;
            *(uint4*)(Ztiles + dst) = *(uint4*)r;
        }
    } else {
        int jn = row - 65535;
        *(uint4*)(Xbf + (size_t)jn * 256 + k8 * 8) = *(uint4*)r;
    }
}

// ---------------- stage 1a: big-level GEMM (256x256, dbuf 2-phase) --------
// C = act(A @ B^T + bias) -> fp16. act: tanh for cols [512,768), sigmoid else.
// 8 waves (2 row-halves x 4 col-quarters), per-wave 128x64 output.
// LDS: 2 buffers x (A 256x64 + B 256x64) bf16, XOR-swizzled = 128 KB dynamic.
// Schedule per k-step: STAGE(t+1) issue -> ds_read+MFMA(t) -> syncthreads
// (vmcnt(0) drains the prefetch under the compute, not before it).
// Requires M % 256 == 0, NC % 256 == 0 (true for leaf + d>=13 levels).
template<int KD, int NC>
__global__ __launch_bounds__(512, 2) void gate_gemm_big(
    const u16* __restrict__ A, const u16* __restrict__ B,
    const float* __restrict__ bias, _Float16* __restrict__ G)
{
    constexpr int NT = KD / 64;
    extern __shared__ u16 S[];           // [2][A:16384 | B:16384]

    const int tid  = threadIdx.x;
    const int wave = tid >> 6;
    const int lane = tid & 63;
    const int bm = blockIdx.x * 256;
    const int bn = blockIdx.y * 256;

    const int srow = lane >> 3;                    // row within 8-row group
    const int scol = ((lane & 7) ^ srow) * 8;      // swizzled source col

    const int wr = wave >> 2;            // 0..1 : 128-row half
    const int wc = wave & 3;             // 0..3 : 64-col quarter
    const int lm = lane & 15, q4 = lane >> 4;

    auto stage = [&](int bi, int t) {
#pragma unroll
        for (int q = 0; q < 4; ++q) {
            const int g = wave * 4 + q;            // 0..31 (8 rows each)
            const int r = g * 8 + srow;            // 0..255
            gld_lds16(A + (size_t)(bm + r) * KD + t * 64 + scol,
                      S + bi * 32768 + g * 512 + lane * 8);
            gld_lds16(B + (size_t)(bn + r) * KD + t * 64 + scol,
                      S + bi * 32768 + 16384 + g * 512 + lane * 8);
        }
    };

    f32x4 acc[8][4] = {};

    stage(0, 0);
    __syncthreads();                      // vmcnt(0) + barrier: buf0 ready

#pragma unroll
    for (int t = 0; t < NT; ++t) {
        if (t + 1 < NT) stage((t + 1) & 1, t + 1);   // prefetch under compute

        const u16* Ab = S + (t & 1) * 32768;
        const u16* Bb = Ab + 16384;
#pragma unroll
        for (int kk = 0; kk < 64; kk += 32) {
            const int sw = ((((kk >> 3) + q4) ^ (lm & 7)) << 3);
            bf16x8 af[8], bfr[4];
#pragma unroll
            for (int i = 0; i < 8; i++)
                af[i] = *(const bf16x8*)(Ab + (wr * 128 + i * 16 + lm) * 64 + sw);
#pragma unroll
            for (int j = 0; j < 4; j++)
                bfr[j] = *(const bf16x8*)(Bb + (wc * 64 + j * 16 + lm) * 64 + sw);
#pragma unroll
            for (int i = 0; i < 8; i++)
#pragma unroll
                for (int j = 0; j < 4; j++)
                    acc[i][j] = __builtin_amdgcn_mfma_f32_16x16x32_bf16(
                        af[i], bfr[j], acc[i][j], 0, 0, 0);
        }
        __syncthreads();                  // drains prefetch (already in flight)
    }

    // epilogue: activate + store fp16
    const int cr0 = q4 * 4;
#pragma unroll
    for (int i = 0; i < 8; i++) {
#pragma unroll
        for (int j = 0; j < 4; j++) {
            const int cg = bn + wc * 64 + j * 16 + lm;
            const float bb = bias[cg];
            const bool istan = ((cg >> 8) == 2);
#pragma unroll
            for (int reg = 0; reg < 4; reg++) {
                const int rr = bm + wr * 128 + i * 16 + cr0 + reg;
                float v = acc[i][j][reg] + bb;
                G[(size_t)rr * NC + cg] =
                    (_Float16)(istan ? fast_tanh(v) : fast_sig(v));
            }
        }
    }
}

// ---------------- stage 1b: small-level gate GEMM (R10 128x128) -----------
__global__ __launch_bounds__(256) void gate_gemm(
    const u16* __restrict__ A, int lda, int M,
    const u16* __restrict__ B, int ldb, int Kdim,
    const float* __restrict__ bias, _Float16* __restrict__ G, int NC)
{
    __shared__ u16 As[128 * 64];
    __shared__ u16 Bs[128 * 64];

    const int tid  = threadIdx.x;
    const int wave = tid >> 6;
    const int lane = tid & 63;
    const int bm = blockIdx.x * 128;
    const int bn = blockIdx.y * 128;

    const int wm = (wave >> 1) * 64;
    const int wn = (wave & 1) * 64;
    const int lm = lane & 15;
    const int q4 = lane >> 4;

    const int srow = lane >> 3;
    const int scol = ((lane & 7) ^ srow) * 8;

    f32x4 acc[4][4] = {};

    for (int k0 = 0; k0 < Kdim; k0 += 64) {
#pragma unroll
        for (int q = 0; q < 4; ++q) {
            const int grp = wave * 4 + q;
            const int r = grp * 8 + srow;
            gld_lds16(A + (size_t)(bm + r) * lda + k0 + scol,
                      As + (size_t)grp * 512 + lane * 8);
            gld_lds16(B + (size_t)(bn + r) * ldb + k0 + scol,
                      Bs + (size_t)grp * 512 + lane * 8);
        }
        __syncthreads();

#pragma unroll
        for (int kk = 0; kk < 64; kk += 32) {
            const int sw = (((kk >> 3) + q4) ^ (lm & 7)) << 3;
            bf16x8 af[4], bfr[4];
#pragma unroll
            for (int i = 0; i < 4; i++)
                af[i] = *(const bf16x8*)(As + (wm + i * 16 + lm) * 64 + sw);
#pragma unroll
            for (int j = 0; j < 4; j++)
                bfr[j] = *(const bf16x8*)(Bs + (wn + j * 16 + lm) * 64 + sw);
#pragma unroll
            for (int i = 0; i < 4; i++)
#pragma unroll
                for (int j = 0; j < 4; j++)
                    acc[i][j] = __builtin_amdgcn_mfma_f32_16x16x32_bf16(
                        af[i], bfr[j], acc[i][j], 0, 0, 0);
        }
        __syncthreads();
    }

    const int cr0 = q4 * 4;
    const int ccc = lm;
#pragma unroll
    for (int i = 0; i < 4; i++) {
#pragma unroll
        for (int reg = 0; reg < 4; reg++) {
            int r = bm + wm + i * 16 + cr0 + reg;
            if (r >= M) continue;
#pragma unroll
            for (int j = 0; j < 4; j++) {
                int cn = bn + wn + j * 16 + ccc;
                float v = acc[i][j][reg] + bias[cn];
                float a = ((cn >> 8) == 2) ? fast_tanh(v) : fast_sig(v);
                G[(size_t)r * NC + cn] = (_Float16)a;
            }
        }
    }
}

// ---------------- stage 2: combine ----------------
template<bool LEAF>
__global__ __launch_bounds__(256) void combine(
    const _Float16* __restrict__ G, const float* __restrict__ csrc,
    float* __restrict__ cdst, u16* __restrict__ zrow_parent,
    u16* __restrict__ zfrag_parent)
{
    constexpr int NC = LEAF ? 768 : 1280;
    const int p = blockIdx.x, h = threadIdx.x;
    const _Float16* G0 = G + (size_t)(2 * p) * NC;
    const _Float16* G1 = G0 + NC;
    float i0 = (float)G0[h], o0 = (float)G0[256 + h], u0 = (float)G0[512 + h];
    float i1 = (float)G1[h], o1 = (float)G1[256 + h], u1 = (float)G1[512 + h];
    float c0 = i0 * u0, c1 = i1 * u1;
    if (!LEAF) {
        float f00 = (float)G0[768 + h], f10 = (float)G0[1024 + h];
        float f01 = (float)G1[768 + h], f11 = (float)G1[1024 + h];
        c0 += f00 * csrc[(size_t)(4 * p) * 256 + h]
            + f10 * csrc[(size_t)(4 * p + 1) * 256 + h];
        c1 += f01 * csrc[(size_t)(4 * p + 2) * 256 + h]
            + f11 * csrc[(size_t)(4 * p + 3) * 256 + h];
    }
    float h0 = o0 * fast_tanh(c0), h1 = o1 * fast_tanh(c1);
    cdst[(size_t)(2 * p) * 256 + h] = c0;
    cdst[(size_t)(2 * p) * 256 + 256 + h] = c1;
    u16 hs = f2bf(h0 + h1);
    if (zrow_parent) {
        zrow_parent[(size_t)p * 512 + 256 + h] = hs;
    } else {
        size_t a = (((size_t)8 + (h >> 5)) * 64
                    + (p & 15) + (((h >> 3) & 3) << 4)) * 8 + (h & 7);
        zfrag_parent[a] = hs;
    }
}

// ---------------- small levels (n<=16): gate-parallel GEMM -> pre ----------
__global__ __launch_bounds__(64) void small_gemm(
    const u16* __restrict__ Zpk, const u16* __restrict__ Wfrag,
    const float* __restrict__ bias, float* __restrict__ pre, int n)
{
    const int lane = threadIdx.x;
    const int q = blockIdx.x;
    const int nt0 = (q >> 2) * 16 + (q & 3) * 4;
    const int cc = lane & 15, rq = (lane >> 4) * 4;

    f32x4 acc[4] = {};
    const u16* aB = Zpk + (size_t)lane * 8;
    const u16* bB = Wfrag + ((size_t)nt0 * 16 * 64 + lane) * 8;

    bf16x8 aX, bX[4], aY, bY[4];
    aX = *(const bf16x8*)(aB);
#pragma unroll
    for (int j = 0; j < 4; ++j)
        bX[j] = *(const bf16x8*)(bB + (size_t)(j * 16) * 512);

#pragma unroll
    for (int kc = 0; kc < 16; kc += 2) {
        aY = *(const bf16x8*)(aB + (size_t)(kc + 1) * 512);
#pragma unroll
        for (int j = 0; j < 4; ++j)
            bY[j] = *(const bf16x8*)(bB + (size_t)(j * 16 + kc + 1) * 512);
#pragma unroll
        for (int j = 0; j < 4; ++j)
            acc[j] = __builtin_amdgcn_mfma_f32_16x16x32_bf16(aX, bX[j], acc[j], 0, 0, 0);
        if (kc + 2 < 16) {
            aX = *(const bf16x8*)(aB + (size_t)(kc + 2) * 512);
#pragma unroll
            for (int j = 0; j < 4; ++j)
                bX[j] = *(const bf16x8*)(bB + (size_t)(j * 16 + kc + 2) * 512);
        }
#pragma unroll
        for (int j = 0; j < 4; ++j)
            acc[j] = __builtin_amdgcn_mfma_f32_16x16x32_bf16(aY, bY[j], acc[j], 0, 0, 0);
    }

#pragma unroll
    for (int j = 0; j < 4; ++j) {
        int coln = (nt0 + j) * 16 + cc;
        float bb = bias[coln];
#pragma unroll
        for (int r = 0; r < 4; ++r) {
            int row = rq + r;
            if (row < n) pre[(size_t)row * 1280 + coln] = acc[j][r] + bb;
        }
    }
}

// ---------------- small-level epilogue (pre -> c, Hs; root -> out) ----------
__global__ __launch_bounds__(256) void epi_small(
    const float* __restrict__ pre, const float* __restrict__ csrc,
    float* __restrict__ c_out, u16* __restrict__ zfrag_parent,
    float* __restrict__ root_out, int npairs)
{
    int idx = blockIdx.x * 256 + threadIdx.x;
    if (root_out) {
        int h = idx;  // 256 threads
        const float* p = pre;
        float c = fast_sig(p[h]) * fast_tanh(p[512 + h])
                + fast_sig(p[768 + h]) * csrc[h]
                + fast_sig(p[1024 + h]) * csrc[256 + h];
        root_out[h] = fast_sig(p[256 + h]) * fast_tanh(c);
        root_out[256 + h] = c;
        return;
    }
    if (idx >= npairs * 256) return;
    int pI = idx >> 8, h = idx & 255;
    int n0 = 2 * pI;
    const float* p0 = pre + (size_t)n0 * 1280;
    const float* p1 = p0 + 1280;
    float c0 = fast_sig(p0[h]) * fast_tanh(p0[512 + h])
             + fast_sig(p0[768 + h]) * csrc[(size_t)(2 * n0) * 256 + h]
             + fast_sig(p0[1024 + h]) * csrc[(size_t)(2 * n0 + 1) * 256 + h];
    float c1 = fast_sig(p1[h]) * fast_tanh(p1[512 + h])
             + fast_sig(p1[768 + h]) * csrc[(size_t)(2 * n0 + 2) * 256 + h]
             + fast_sig(p1[1024 + h]) * csrc[(size_t)(2 * n0 + 3) * 256 + h];
    float h0 = fast_sig(p0[256 + h]) * fast_tanh(c0);
    float h1 = fast_sig(p1[256 + h]) * fast_tanh(c1);
    c_out[(size_t)n0 * 256 + h] = c0;
    c_out[(size_t)(n0 + 1) * 256 + h] = c1;
    size_t a = (((size_t)8 + (h >> 5)) * 64
                + (pI & 15) + (((h >> 3) & 3) << 4)) * 8 + (h & 7);
    zfrag_parent[a] = f2bf(h0 + h1);
}

// ---------------- launch ----------------
extern "C" void kernel_launch(void* const* d_in, const int* in_sizes, int n_in,
                              void* d_out, int out_size, void* d_ws, size_t ws_size,
                              hipStream_t stream)
{
    const float* x   = (const float*)d_in[0];
    const float* Wi  = (const float*)d_in[1];
    const float* bi  = (const float*)d_in[2];
    const float* Wf  = (const float*)d_in[3];
    const float* bf  = (const float*)d_in[4];
    const float* Wo  = (const float*)d_in[5];
    const float* bo  = (const float*)d_in[6];
    const float* Wu  = (const float*)d_in[7];
    const float* bu  = (const float*)d_in[8];
    const float* Ui  = (const float*)d_in[9];
    const float* Uo  = (const float*)d_in[10];
    const float* Uu  = (const float*)d_in[11];
    const float* Wfk = (const float*)d_in[12];
    float* out = (float*)d_out;
    char* ws   = (char*)d_ws;
    (void)ws_size; (void)in_sizes; (void)n_in; (void)out_size;

    size_t off = 0;
    u16* Wrow     = (u16*)(ws + off); off += (size_t)1280 * 512 * 2;
    u16* Wfrag    = (u16*)(ws + off); off += (size_t)1280 * 512 * 2;
    u16* WleafRow = (u16*)(ws + off); off += (size_t)768 * 256 * 2;
    float* bbig   = (float*)(ws + off); off += 1280 * 4;
    float* bleaf  = (float*)(ws + off); off += 768 * 4 + 192;                // 256B align
    u16* Xbf    = (u16*)(ws + off); off += (size_t)65536 * 256 * 2;          // 32 MB
    u16* Zrow   = (u16*)(ws + off); off += (size_t)65536 * 512 * 2;          // 64 MB
    u16* Ztiles = (u16*)(ws + off); off += (size_t)5 * 8192 * 2;             // 80 KB
    float* cA = (float*)(ws + off); off += (size_t)65536 * 256 * 4;          // 64 MB
    float* cB = (float*)(ws + off); off += (size_t)32768 * 256 * 4;          // 32 MB
    float* pre_small = (float*)(ws + off); off += (size_t)16 * 1280 * 4;
    _Float16* Ghalf = (_Float16*)(ws + off); off += (size_t)65536 * 768 * 2; // 96 MB

    auto ztile = [&](int d) -> u16* { return Ztiles + (size_t)(4 - d) * 8192; };

    // allow 128KB dynamic LDS for the big gemm (host-side, graph-safe)
    static bool attr_set = false;
    if (!attr_set) {
        hipFuncSetAttribute((const void*)gate_gemm_big<512, 1280>,
                            hipFuncAttributeMaxDynamicSharedMemorySize, 131072);
        hipFuncSetAttribute((const void*)gate_gemm_big<256, 768>,
                            hipFuncAttributeMaxDynamicSharedMemorySize, 131072);
        attr_set = true;
    }

    // 1) pack weights + convert x
    pack_weights<<<5897, 256, 0, stream>>>(Wi, bi, Wf, bf, Wo, bo, Wu, bu,
                                           Ui, Uo, Uu, Wfk, Wrow, Wfrag, WleafRow,
                                           bbig, bleaf);
    cvt_all<<<16385, 256, 0, stream>>>(x, Zrow, Ztiles, Xbf);

    // 2) leaf: gemm (i,o,u fp16) + combine -> cA, Hs into Zrow level 15
    gate_gemm_big<256, 768><<<dim3(LEAF_N / 256, 3), 512, 131072, stream>>>(
        Xbf, WleafRow, bleaf, Ghalf);
    combine<true><<<LEAF_N / 2, 256, 0, stream>>>(
        Ghalf, nullptr, cA, Zrow + zrowOff(15), nullptr);

    // 3) internal levels d=15..5
    for (int d = 15; d >= 5; d--) {
        int n = 1 << d;
        float* csrc = (d & 1) ? cA : cB;
        float* cdst = (d & 1) ? cB : cA;
        if (d >= 13) {
            gate_gemm_big<512, 1280><<<dim3(n / 256, 5), 512, 131072, stream>>>(
                Zrow + zrowOff(d), Wrow, bbig, Ghalf);
        } else {
            gate_gemm<<<dim3((n + 127) / 128, 10), 256, 0, stream>>>(
                Zrow + zrowOff(d), 512, n, Wrow, 512, 512, bbig, Ghalf, 1280);
        }
        if (d >= 6)
            combine<false><<<n / 2, 256, 0, stream>>>(
                Ghalf, csrc, cdst, Zrow + zrowOff(d - 1), nullptr);
        else
            combine<false><<<n / 2, 256, 0, stream>>>(
                Ghalf, csrc, cdst, nullptr, ztile(4));
    }

    // 4) small levels d=4..1: frag-major gate-parallel gemm + epilogue
    for (int d = 4; d >= 1; d--) {
        int n = 1 << d;
        float* csrc = (d & 1) ? cA : cB;
        float* cdst = (d & 1) ? cB : cA;
        small_gemm<<<20, 64, 0, stream>>>(ztile(d), Wfrag, bbig, pre_small, n);
        epi_small<<<n / 2, 256, 0, stream>>>(pre_small, csrc, cdst,
                                             ztile(d - 1), nullptr, n / 2);
    }

    // 5) root: gemm + epilogue straight to out = [h(256)|c(256)]
    small_gemm<<<20, 64, 0, stream>>>(ztile(0), Wfrag, bbig, pre_small, 1);
    epi_small<<<1, 256, 0, stream>>>(pre_small, cB, nullptr, nullptr, out, 0);
}